// Round 3
// baseline (115.301 us; speedup 1.0000x reference)
//
#include <hip/hip_runtime.h>

// y: [B=8, C=192, H=64, W=64] f32; codebooks: [G=8, K=512, d=24] f32
// out (f32, concat): universal_ctx | y_ba | code_index [B,1,G,H,W]
// Single fused kernel. Each block builds its group's 26 KiB LDS image, then each
// wave screens its TWO position-tiles in one fused pass (shared eh/e2 LDS reads).
#define B_   8
#define C_   192
#define HW_  4096
#define G_   8
#define K_   512
#define D_   24
#define CBSZ (K_ * D_)
#define THREADS 512              // 8 waves/block
#define NBLOCKS 1024             // 4 blocks/CU * 256 CU, one fully-resident round

// Per-group LDS image, halfword units:
//   frag region: 32 tiles * 384 hw = 12288 hw (24576 B) -- bf16-hi code fragments
//   e2 region:   512 f32 (2048 B) of (256.0 + ||e_n||^2), exact f32, pre-biased
#define FRAG_HW   12288
#define IMG_HW    13312          // 26624 B -> 4 blocks/CU by LDS, 32 waves/CU

typedef float  f32x4 __attribute__((ext_vector_type(4)));
typedef int    i32x4 __attribute__((ext_vector_type(4)));
typedef short  s16x8 __attribute__((ext_vector_type(8)));
typedef short  s16x4 __attribute__((ext_vector_type(4)));
typedef unsigned long long u64;

static __device__ __forceinline__ unsigned umin_(unsigned a, unsigned b){return a<b?a:b;}
static __device__ __forceinline__ unsigned umax_(unsigned a, unsigned b){return a>b?a:b;}
static __device__ __forceinline__ unsigned short f2bf(float x){       // RNE f32->bf16
    unsigned u=__float_as_uint(x);
    return (unsigned short)((u + 0x7FFFu + ((u>>16)&1u))>>16);
}

// ------------------------------- fused kernel --------------------------------
__global__ __launch_bounds__(THREADS, 8) void vq_mfma8(
    const float* __restrict__ y, const float* __restrict__ cb,
    float* __restrict__ out)
{
    __shared__ __align__(16) unsigned short sB[IMG_HW];   // 26624 B

    const int bid = blockIdx.x;
    const int g = bid & 7;                     // all blocks of a group share an XCD
    const int blkg = bid >> 3;                 // 128 blocks per group
    const int tid = threadIdx.x;
    const int wave = tid >> 6, lane = tid & 63;
    const int c = lane & 15, q = lane >> 4;

    const float* cbg = cb + g * CBSZ;

    // ---- staging: one codebook row per thread (coalesced f32x4), feeds both
    //      the bf16 fragment image and the exact-f32 e2 norm ----
    {
        const int n = tid;                     // 512 threads == 512 codes
        const f32x4* row4 = (const f32x4*)(cbg + n * D_);
        f32x4 rr[6];
        #pragma unroll
        for (int kb = 0; kb < 6; ++kb) rr[kb] = row4[kb];
        const int nb = (n >> 4) * 384 + (n & 15) * 8;
        #pragma unroll
        for (int kb = 0; kb < 6; ++kb) {
            const int k0 = kb * 4;
            const int off = nb + ((k0 >> 3) << 7) + (k0 & 7);
            s16x4 h;
            h[0]=(short)f2bf(rr[kb][0]); h[1]=(short)f2bf(rr[kb][1]);
            h[2]=(short)f2bf(rr[kb][2]); h[3]=(short)f2bf(rr[kb][3]);
            *(s16x4*)(&sB[off]) = h;           // 8B-aligned (k0&7 in {0,4})
        }
        double s0 = 0.0, s1 = 0.0;             // same accumulation order as before
        #pragma unroll
        for (int kb = 0; kb < 6; ++kb) {
            double v0=(double)rr[kb][0], v1=(double)rr[kb][1];
            double v2=(double)rr[kb][2], v3=(double)rr[kb][3];
            s0 = fma(v0,v0,s0); s1 = fma(v1,v1,s1);
            s0 = fma(v2,v2,s0); s1 = fma(v3,v3,s1);
        }
        ((float*)(sB + FRAG_HW))[n] = (float)(256.0 + s0 + s1);
    }
    __syncthreads();

    float* out0 = out;
    float* out1 = out + B_*C_*HW_;
    float* out2 = out + 2*B_*C_*HW_;

    // A-fragment pointer: lanes 48..63 alias lanes 0..15 (finite data; their
    // k=24..31 products multiply a zero B operand, contributing nothing).
    const unsigned short* aptr = sB + (lane < 48 ? lane : lane - 48) * 8;
    // e2 accumulator-init pointer: lane (c,q) reg r -> code t*16 + q*4 + r
    const f32x4* e2p = (const f32x4*)((const float*)(sB + FRAG_HW) + (q << 2));
    const unsigned qr4 = (unsigned)(q << 2);

    // wave owns tiles wsid and wsid+1024 (same hw, bimg and bimg+4)
    const int wsid  = (blkg << 3) + wave;      // [0,1024)
    const int hw    = (wsid & 255) << 4;
    const int bimg0 = wsid >> 8;               // 0..3
    int ybase[2];
    ybase[0] = (bimg0*C_ + g*D_)*HW_ + hw;
    ybase[1] = ybase[0] + 4*C_*HW_;

    // ---- B operands for both tiles: lane (c,q<3) holds (-2x)[pos c][k=q*8+j] ----
    s16x8 Xh[2], Xl[2];
    #pragma unroll
    for (int ti = 0; ti < 2; ++ti) {
        unsigned hx[4], lx[4];
        if (q < 3) {
            const float* yq = y + ybase[ti] + (q*8)*HW_ + c;
            float xf[8];
            #pragma unroll
            for (int jj = 0; jj < 8; ++jj) xf[jj] = -2.0f * yq[jj*HW_];
            #pragma unroll
            for (int p2 = 0; p2 < 4; ++p2) {
                float f0 = xf[2*p2], f1 = xf[2*p2+1];
                unsigned u0 = __float_as_uint(f0), u1v = __float_as_uint(f1);
                hx[p2] = (u1v & 0xFFFF0000u) | (u0 >> 16);        // trunc-hi pair
                float l0 = f0 - __uint_as_float(u0 & 0xFFFF0000u);
                float l1 = f1 - __uint_as_float(u1v & 0xFFFF0000u);
                lx[p2] = (unsigned)f2bf(l0) | ((unsigned)f2bf(l1) << 16);
            }
        } else {
            hx[0]=0u; hx[1]=0u; hx[2]=0u; hx[3]=0u;
            lx[0]=0u; lx[1]=0u; lx[2]=0u; lx[3]=0u;
        }
        Xh[ti] = __builtin_bit_cast(s16x8, (i32x4){(int)hx[0],(int)hx[1],(int)hx[2],(int)hx[3]});
        Xl[ti] = __builtin_bit_cast(s16x8, (i32x4){(int)lx[0],(int)lx[1],(int)lx[2],(int)lx[3]});
    }

    // ---- fused screen: one eh/e2 read feeds BOTH tiles (4 MFMAs per t).
    //      Per-lane top-3 via v_med3_u32; id = (t<<4)|r in-loop (compile-time
    //      literal), q<<2 added once before the butterfly. ----
    unsigned b1a[2] = {0xFFFFFFFFu, 0xFFFFFFFFu};
    unsigned b2a[2] = {0xFFFFFFFFu, 0xFFFFFFFFu};
    unsigned b3a[2] = {0xFFFFFFFFu, 0xFFFFFFFFu};
    #pragma unroll 4
    for (int t = 0; t < 32; ++t) {
        s16x8 eh  = *(const s16x8*)(aptr + t * 384);
        f32x4 e2v = e2p[t * 4];                // broadcast ds_read_b128
        f32x4 a0 = __builtin_amdgcn_mfma_f32_16x16x32_bf16(eh, Xh[0], e2v, 0,0,0);
        a0       = __builtin_amdgcn_mfma_f32_16x16x32_bf16(eh, Xl[0], a0,  0,0,0);
        f32x4 a1 = __builtin_amdgcn_mfma_f32_16x16x32_bf16(eh, Xh[1], e2v, 0,0,0);
        a1       = __builtin_amdgcn_mfma_f32_16x16x32_bf16(eh, Xl[1], a1,  0,0,0);
        #pragma unroll
        for (int r = 0; r < 4; ++r) {
            const unsigned idtr = (unsigned)((t << 4) | r);   // compile-time
            {
                unsigned key = (__float_as_uint(a0[r]) & 0xFFFFFE00u) + idtr;
                unsigned t3, t2;
                asm("v_med3_u32 %0, %1, %2, %3" : "=v"(t3) : "v"(key), "v"(b2a[0]), "v"(b3a[0]));
                asm("v_med3_u32 %0, %1, %2, %3" : "=v"(t2) : "v"(key), "v"(b1a[0]), "v"(b2a[0]));
                b3a[0] = t3; b2a[0] = t2; b1a[0] = umin_(b1a[0], key);
            }
            {
                unsigned key = (__float_as_uint(a1[r]) & 0xFFFFFE00u) + idtr;
                unsigned t3, t2;
                asm("v_med3_u32 %0, %1, %2, %3" : "=v"(t3) : "v"(key), "v"(b2a[1]), "v"(b3a[1]));
                asm("v_med3_u32 %0, %1, %2, %3" : "=v"(t2) : "v"(key), "v"(b1a[1]), "v"(b2a[1]));
                b3a[1] = t3; b2a[1] = t2; b1a[1] = umin_(b1a[1], key);
            }
        }
    }
    #pragma unroll
    for (int ti = 0; ti < 2; ++ti) {           // embed q before cross-q merge
        b1a[ti] += qr4; b2a[ti] += qr4; b3a[ti] += qr4;
    }

    // ---- per-tile tail: butterfly, gate, recheck, epilogue ----
    #pragma unroll
    for (int ti = 0; ti < 2; ++ti) {
        unsigned b1 = b1a[ti], b2 = b2a[ti], b3 = b3a[ti];
        #pragma unroll
        for (int d = 16; d < 64; d <<= 1) {    // 2-step butterfly: global top-3
            unsigned o1=__shfl_xor(b1,d,64), o2=__shfl_xor(b2,d,64), o3=__shfl_xor(b3,d,64);
            unsigned x = umax_(b1,o1);
            unsigned yv= umin_(b2,o2);
            unsigned w = umax_(b2,o2);
            unsigned z = umin_(b3,o3);
            b1 = umin_(b1,o1);
            b2 = umin_(x,yv);
            b3 = umin_(umax_(x,yv), umin_(w,z));
        }

        const float v1 = __uint_as_float(b1 & 0xFFFFFE00u);
        const float v2 = __uint_as_float(b2 & 0xFFFFFE00u);
        int kwin;
        if (__ballot((v2 - v1) < 0.20f) == 0ull) {
            kwin = (int)(b1 & 511u);
        } else {
            // re-derive -2x from y (L1-hot; bitwise-identical to prep-time xf)
            float xfr[8];
            if (q < 3) {
                const float* yq = y + ybase[ti] + (q*8)*HW_ + c;
                #pragma unroll
                for (int jj = 0; jj < 8; ++jj) xfr[jj] = -2.0f * yq[jj*HW_];
            } else {
                #pragma unroll
                for (int jj = 0; jj < 8; ++jj) xfr[jj] = 0.0f;
            }
            double xd[8];
            #pragma unroll
            for (int jj = 0; jj < 8; ++jj) xd[jj] = (double)xfr[jj];
            const unsigned cands[3] = {b1, b2, b3};
            u64 bestk = ~0ull;
            #pragma unroll
            for (int ci = 0; ci < 3; ++ci) {
                int kc = (int)(cands[ci] & 511u);
                double s = 0.0;
                if (q < 3) {
                    const f32x4* ce4 = (const f32x4*)(cbg + kc*D_ + (q<<3));
                    float ef[8];
                    *(f32x4*)&ef[0] = ce4[0];
                    *(f32x4*)&ef[4] = ce4[1];
                    #pragma unroll
                    for (int jj = 0; jj < 8; ++jj) {
                        double ev = (double)ef[jj];
                        s = fma(ev, ev, s);
                        s = fma(xd[jj], ev, s);
                    }
                }
                s += __shfl_xor(s, 16, 64);
                s += __shfl_xor(s, 32, 64);
                s += 256.0;
                u64 kk = (((u64)__double_as_longlong(s)) & ~0x1FFull) | (u64)kc;
                bestk = kk < bestk ? kk : bestk;
            }
            kwin = (int)(bestk & 511ull);
        }

        // epilogue: lane (c,q<3) writes dims q*8..q*8+7 of pos c
        const float* cw = cbg + kwin * D_;
        if (q < 3) {
            const f32x4* cw4 = (const f32x4*)(cw + (q<<3));
            float v[8];
            *(f32x4*)&v[0] = cw4[0];
            *(f32x4*)&v[4] = cw4[1];
            const int ob = ybase[ti] + (q*8)*HW_ + c;
            #pragma unroll
            for (int jj = 0; jj < 8; ++jj) {
                out0[ob + jj*HW_] = v[jj];
                out1[ob + jj*HW_] = v[jj];
            }
        }
        if (lane < 16) {
            const int bimg = bimg0 + ti*4;
            out2[(bimg*G_ + g)*HW_ + hw + lane] = (float)kwin;
        }
    }
}

extern "C" void kernel_launch(void* const* d_in, const int* in_sizes, int n_in,
                              void* d_out, int out_size, void* d_ws, size_t ws_size,
                              hipStream_t stream) {
    const float* y  = (const float*)d_in[0];
    const float* cb = (const float*)d_in[1];
    float* out = (float*)d_out;
    (void)d_ws; (void)ws_size;                 // fully fused; ws unused

    vq_mfma8<<<dim3(NBLOCKS), dim3(THREADS), 0, stream>>>(y, cb, out);
}

// Round 4
// 113.863 us; speedup vs baseline: 1.0126x; 1.0126x over previous
//
#include <hip/hip_runtime.h>

// y: [B=8, C=192, H=64, W=64] f32; codebooks: [G=8, K=512, d=24] f32
// out (f32, concat): universal_ctx | y_ba | code_index [B,1,G,H,W]
// Two kernels. Stage prebuilds per-group images in ws: eh-frag + exact e2
// (26624 B/group, 208 KiB total -- always fits), plus el-frag (lo-part bf16,
// 24576 B/group) iff ws_size >= 400 KiB. Main kernel: coalesced copy to LDS,
// 3-product MFMA screen (eh*xh + eh*xl + el*xh, err ~2e-3), 7-bit in-lane id
// (quant 2^-8), rare exact-f64 recheck (gate 0.03125).
#define B_   8
#define C_   192
#define HW_  4096
#define G_   8
#define K_   512
#define D_   24
#define CBSZ (K_ * D_)
#define THREADS 512              // 8 waves/block
#define NBLOCKS 512              // 2 blocks/CU; 64 blocks/group; 4 tiles/wave exact

// LDS layout (halfword units): [eh frag 12288][e2 512*f32 =1024][el frag 12288]
#define FRAG_HW    12288         // 32 t * 384 hw
#define E2_OFF_HW  12288
#define EL_OFF_HW  13312
#define IMG_HW     25600         // 51200 B -> 2 blocks/CU (3 possible)
// ws layout: 8 * [eh+e2 13312 hw] then 8 * [el 12288 hw]
#define WS_IMG_HW  13312
#define WS_EL_BASE (8 * WS_IMG_HW)
#define WS_BIG_BYTES ((8 * WS_IMG_HW + 8 * FRAG_HW) * 2)   // 409600

typedef float  f32x4 __attribute__((ext_vector_type(4)));
typedef int    i32x4 __attribute__((ext_vector_type(4)));
typedef short  s16x8 __attribute__((ext_vector_type(8)));
typedef short  s16x4 __attribute__((ext_vector_type(4)));
typedef unsigned long long u64;

static __device__ __forceinline__ unsigned umin_(unsigned a, unsigned b){return a<b?a:b;}
static __device__ __forceinline__ unsigned umax_(unsigned a, unsigned b){return a>b?a:b;}
static __device__ __forceinline__ unsigned short f2bf(float x){       // RNE f32->bf16
    unsigned u=__float_as_uint(x);
    return (unsigned short)((u + 0x7FFFu + ((u>>16)&1u))>>16);
}
static __device__ __forceinline__ float bf2f(unsigned short h){return __uint_as_float(((unsigned)h)<<16);}
// packed id9 = t<<4 | r<<2 | q  ->  code number = t*16 + q*4 + r
static __device__ __forceinline__ int dec_id(unsigned idb){
    return (int)((idb & 0x1F0u) | ((idb & 3u) << 2) | ((idb >> 2) & 3u));
}

// ---------- stage: build per-group images in ws ----------
// frag: idx = t*384 + ((k>>3)*16 + (n&15))*8 + (k&7); e2 exact f32, +256 bias
__global__ __launch_bounds__(256) void vq_stage(
    const float* __restrict__ cb, unsigned short* __restrict__ ws, int wr_el)
{
    const int g = blockIdx.x >> 3;
    const int s = blockIdx.x & 7;              // 64-code slice of this group
    const int tid = threadIdx.x;
    const float* cbg = cb + g * CBSZ;
    unsigned short* img = ws + g * WS_IMG_HW;
    unsigned short* eli = ws + WS_EL_BASE + g * FRAG_HW;

    for (int i = tid; i < 384; i += 256) {
        int gi = s * 384 + i;
        f32x4 v = ((const f32x4*)cbg)[gi];
        int i4 = gi << 2;
        int n  = i4 / 24;                      // float4 never crosses a row
        int k0 = i4 - n * 24;
        int off = (n >> 4) * 384 + (((k0 >> 3) << 4) + (n & 15)) * 8 + (k0 & 7);
        s16x4 h, l;
        #pragma unroll
        for (int j = 0; j < 4; ++j) {
            unsigned short eh = f2bf(v[j]);
            h[j] = (short)eh;
            l[j] = (short)f2bf(v[j] - bf2f(eh));
        }
        *(s16x4*)(&img[off]) = h;              // 8B-aligned (k0&7 in {0,4})
        if (wr_el) *(s16x4*)(&eli[off]) = l;
    }
    if (tid < 64) {
        int n = s * 64 + tid;
        const float* row = cbg + n * D_;
        double s0 = 0.0, s1 = 0.0;
        #pragma unroll
        for (int j = 0; j < D_; j += 2) {
            double v0 = (double)row[j], v1 = (double)row[j+1];
            s0 = fma(v0,v0,s0); s1 = fma(v1,v1,s1);
        }
        ((float*)(img + E2_OFF_HW))[n] = (float)(256.0 + s0 + s1);
    }
}

// ------------------------------- main kernel ---------------------------------
template<bool ELWS>
__global__ __launch_bounds__(THREADS, 4) void vq_main(
    const float* __restrict__ y, const float* __restrict__ cb,
    const unsigned short* __restrict__ ws, float* __restrict__ out)
{
    __shared__ __align__(16) unsigned short sB[IMG_HW];   // 51200 B

    const int bid = blockIdx.x;
    const int g = bid & 7;                     // group pinned to one XCD
    const int blkg = bid >> 3;                 // 64 blocks per group
    const int tid = threadIdx.x;
    const int wave = tid >> 6, lane = tid & 63;
    const int c = lane & 15, q = lane >> 4;

    const float* cbg = cb + g * CBSZ;

    // ---- staging: coalesced copy of eh+e2 (26624 B) ----
    {
        const char* src = (const char*)(ws + g * WS_IMG_HW);
        char* dst = (char*)sB;
        #pragma unroll
        for (int it = 0; it < 4; ++it) {
            int off = it * 8192 + tid * 16;
            if (off < 26624)
                *(i32x4*)(dst + off) = *(const i32x4*)(src + off);
        }
    }
    if (ELWS) {                                // el frag: coalesced copy 24576 B
        const char* src = (const char*)(ws + WS_EL_BASE + g * FRAG_HW);
        char* dst = (char*)(sB + EL_OFF_HW);
        #pragma unroll
        for (int it = 0; it < 3; ++it) {
            int off = it * 8192 + tid * 16;
            *(i32x4*)(dst + off) = *(const i32x4*)(src + off);
        }
    } else {                                   // build el from cb (coalesced reads)
        #pragma unroll
        for (int it = 0; it < 6; ++it) {
            int gi = it * THREADS + tid;       // 3072 float4s cover the group
            f32x4 v = ((const f32x4*)cbg)[gi];
            int i4 = gi << 2;
            int n  = i4 / 24;
            int k0 = i4 - n * 24;
            int off = (n >> 4) * 384 + (((k0 >> 3) << 4) + (n & 15)) * 8 + (k0 & 7);
            s16x4 l;
            #pragma unroll
            for (int j = 0; j < 4; ++j) {
                unsigned short eh = f2bf(v[j]);
                l[j] = (short)f2bf(v[j] - bf2f(eh));
            }
            *(s16x4*)(&sB[EL_OFF_HW + off]) = l;
        }
    }
    __syncthreads();

    float* out0 = out;
    float* out1 = out + B_*C_*HW_;
    float* out2 = out + 2*B_*C_*HW_;

    // A-fragment pointers: lanes 48..63 alias lanes 0..15 (their k=24..31
    // products multiply a zero B operand).
    const unsigned short* aH = sB + (lane < 48 ? lane : lane - 48) * 8;
    const unsigned short* aL = aH + EL_OFF_HW;
    // e2 accumulator-init: lane (c,q) reg r -> code t*16 + q*4 + r
    const f32x4* e2p = (const f32x4*)((const float*)(sB + E2_OFF_HW) + (q << 2));

    const int wsid = (blkg << 3) + wave;       // [0,512) per group

    #pragma unroll 1
    for (int p = 0; p < 2; ++p) {              // 2 fused pairs = 4 tiles/wave
        const int tt0   = wsid + (p << 10);    // pair tiles: tt0, tt0+512
        const int hw    = (tt0 & 255) << 4;
        const int bimg0 = tt0 >> 8;
        int ybase[2];
        ybase[0] = (bimg0*C_ + g*D_)*HW_ + hw;
        ybase[1] = ybase[0] + 2*C_*HW_;        // bimg0+2

        // ---- B operands: lane (c,q<3) holds (-2x)[pos c][k=q*8+j]; q==3 -> 0 ----
        s16x8 Xh[2], Xl[2];
        #pragma unroll
        for (int ti = 0; ti < 2; ++ti) {
            unsigned hx[4], lx[4];
            if (q < 3) {
                const float* yq = y + ybase[ti] + (q*8)*HW_ + c;
                float xf[8];
                #pragma unroll
                for (int jj = 0; jj < 8; ++jj) xf[jj] = -2.0f * yq[jj*HW_];
                #pragma unroll
                for (int p2 = 0; p2 < 4; ++p2) {
                    float f0 = xf[2*p2], f1 = xf[2*p2+1];
                    unsigned u0 = __float_as_uint(f0), u1v = __float_as_uint(f1);
                    hx[p2] = (u1v & 0xFFFF0000u) | (u0 >> 16);    // trunc-hi pair
                    float l0 = f0 - __uint_as_float(u0 & 0xFFFF0000u);
                    float l1 = f1 - __uint_as_float(u1v & 0xFFFF0000u);
                    lx[p2] = (unsigned)f2bf(l0) | ((unsigned)f2bf(l1) << 16);
                }
            } else {
                hx[0]=0u; hx[1]=0u; hx[2]=0u; hx[3]=0u;
                lx[0]=0u; lx[1]=0u; lx[2]=0u; lx[3]=0u;
            }
            Xh[ti] = __builtin_bit_cast(s16x8, (i32x4){(int)hx[0],(int)hx[1],(int)hx[2],(int)hx[3]});
            Xl[ti] = __builtin_bit_cast(s16x8, (i32x4){(int)lx[0],(int)lx[1],(int)lx[2],(int)lx[3]});
        }

        // ---- fused 3-product screen; in-lane 7-bit id (quant 2^-8) ----
        unsigned b1a[2] = {~0u, ~0u}, b2a[2] = {~0u, ~0u}, b3a[2] = {~0u, ~0u};
        #pragma unroll 4
        for (int t = 0; t < 32; ++t) {
            s16x8 eh  = *(const s16x8*)(aH + t * 384);
            s16x8 el  = *(const s16x8*)(aL + t * 384);
            f32x4 e2v = e2p[t * 4];            // broadcast ds_read_b128
            f32x4 a0 = __builtin_amdgcn_mfma_f32_16x16x32_bf16(eh, Xh[0], e2v, 0,0,0);
            a0       = __builtin_amdgcn_mfma_f32_16x16x32_bf16(eh, Xl[0], a0,  0,0,0);
            a0       = __builtin_amdgcn_mfma_f32_16x16x32_bf16(el, Xh[0], a0,  0,0,0);
            f32x4 a1 = __builtin_amdgcn_mfma_f32_16x16x32_bf16(eh, Xh[1], e2v, 0,0,0);
            a1       = __builtin_amdgcn_mfma_f32_16x16x32_bf16(eh, Xl[1], a1,  0,0,0);
            a1       = __builtin_amdgcn_mfma_f32_16x16x32_bf16(el, Xh[1], a1,  0,0,0);
            #pragma unroll
            for (int r = 0; r < 4; ++r) {
                const unsigned id7 = (unsigned)((t << 2) | r);    // compile-time
                {
                    unsigned key = (__float_as_uint(a0[r]) & 0xFFFFFF80u) + id7;
                    unsigned t3, t2;
                    asm("v_med3_u32 %0, %1, %2, %3" : "=v"(t3) : "v"(key), "v"(b2a[0]), "v"(b3a[0]));
                    asm("v_med3_u32 %0, %1, %2, %3" : "=v"(t2) : "v"(key), "v"(b1a[0]), "v"(b2a[0]));
                    b3a[0] = t3; b2a[0] = t2; b1a[0] = umin_(b1a[0], key);
                }
                {
                    unsigned key = (__float_as_uint(a1[r]) & 0xFFFFFF80u) + id7;
                    unsigned t3, t2;
                    asm("v_med3_u32 %0, %1, %2, %3" : "=v"(t3) : "v"(key), "v"(b2a[1]), "v"(b3a[1]));
                    asm("v_med3_u32 %0, %1, %2, %3" : "=v"(t2) : "v"(key), "v"(b1a[1]), "v"(b2a[1]));
                    b3a[1] = t3; b2a[1] = t2; b1a[1] = umin_(b1a[1], key);
                }
            }
        }

        // ---- per-tile tail ----
        #pragma unroll
        for (int ti = 0; ti < 2; ++ti) {
            // expand to 9-bit id: (b<<2)|q -- order-safe (constant exponent 8)
            unsigned b1 = (b1a[ti] << 2) | (unsigned)q;
            unsigned b2 = (b2a[ti] << 2) | (unsigned)q;
            unsigned b3 = (b3a[ti] << 2) | (unsigned)q;
            #pragma unroll
            for (int d = 16; d < 64; d <<= 1) {   // butterfly: global top-3
                unsigned o1=__shfl_xor(b1,d,64), o2=__shfl_xor(b2,d,64), o3=__shfl_xor(b3,d,64);
                unsigned x = umax_(b1,o1);
                unsigned yv= umin_(b2,o2);
                unsigned w = umax_(b2,o2);
                unsigned z = umin_(b3,o3);
                b1 = umin_(b1,o1);
                b2 = umin_(x,yv);
                b3 = umin_(umax_(x,yv), umin_(w,z));
            }

            // gate: mantissa units of 2^-8; fire if gap < 8 units (0.03125)
            const int gap = (int)((b2 >> 9) - (b1 >> 9));
            int kwin;
            if (__ballot(gap < 8) == 0ull) {
                kwin = dec_id(b1 & 511u);
            } else {
                // exact fp64 recheck (rare): re-derive -2x from y (L2-hot)
                float xfr[8];
                if (q < 3) {
                    const float* yq = y + ybase[ti] + (q*8)*HW_ + c;
                    #pragma unroll
                    for (int jj = 0; jj < 8; ++jj) xfr[jj] = -2.0f * yq[jj*HW_];
                } else {
                    #pragma unroll
                    for (int jj = 0; jj < 8; ++jj) xfr[jj] = 0.0f;
                }
                double xd[8];
                #pragma unroll
                for (int jj = 0; jj < 8; ++jj) xd[jj] = (double)xfr[jj];
                const unsigned cands[3] = {b1, b2, b3};
                u64 bestk = ~0ull;
                #pragma unroll
                for (int ci = 0; ci < 3; ++ci) {
                    int kc = dec_id(cands[ci] & 511u);
                    double s = 0.0;
                    if (q < 3) {
                        const f32x4* ce4 = (const f32x4*)(cbg + kc*D_ + (q<<3));
                        float ef[8];
                        *(f32x4*)&ef[0] = ce4[0];
                        *(f32x4*)&ef[4] = ce4[1];
                        #pragma unroll
                        for (int jj = 0; jj < 8; ++jj) {
                            double ev = (double)ef[jj];
                            s = fma(ev, ev, s);
                            s = fma(xd[jj], ev, s);
                        }
                    }
                    s += __shfl_xor(s, 16, 64);
                    s += __shfl_xor(s, 32, 64);
                    s += 256.0;
                    u64 kk = (((u64)__double_as_longlong(s)) & ~0x1FFull) | (u64)kc;
                    bestk = kk < bestk ? kk : bestk;
                }
                kwin = (int)(bestk & 511ull);
            }

            // epilogue: lane (c,q<3) writes dims q*8..q*8+7 of pos c
            const float* cw = cbg + kwin * D_;
            if (q < 3) {
                const f32x4* cw4 = (const f32x4*)(cw + (q<<3));
                float v[8];
                *(f32x4*)&v[0] = cw4[0];
                *(f32x4*)&v[4] = cw4[1];
                const int ob = ybase[ti] + (q*8)*HW_ + c;
                #pragma unroll
                for (int jj = 0; jj < 8; ++jj) {
                    out0[ob + jj*HW_] = v[jj];
                    out1[ob + jj*HW_] = v[jj];
                }
            }
            if (lane < 16) {
                const int bimg = bimg0 + 2*ti;
                out2[(bimg*G_ + g)*HW_ + hw + lane] = (float)kwin;
            }
        }
    }
}

extern "C" void kernel_launch(void* const* d_in, const int* in_sizes, int n_in,
                              void* d_out, int out_size, void* d_ws, size_t ws_size,
                              hipStream_t stream) {
    const float* y  = (const float*)d_in[0];
    const float* cb = (const float*)d_in[1];
    float* out = (float*)d_out;
    unsigned short* ws = (unsigned short*)d_ws;

    const bool big = ws_size >= (size_t)WS_BIG_BYTES;   // room for el frags too?
    vq_stage<<<dim3(64), dim3(256), 0, stream>>>(cb, ws, big ? 1 : 0);
    if (big) vq_main<true ><<<dim3(NBLOCKS), dim3(THREADS), 0, stream>>>(y, cb, ws, out);
    else     vq_main<false><<<dim3(NBLOCKS), dim3(THREADS), 0, stream>>>(y, cb, ws, out);
}

// Round 5
// 113.234 us; speedup vs baseline: 1.0182x; 1.0055x over previous
//
#include <hip/hip_runtime.h>

// y: [B=8, C=192, H=64, W=64] f32; codebooks: [G=8, K=512, d=24] f32
// out (f32, concat): universal_ctx | y_ba | code_index [B,1,G,H,W]
// Two kernels. Stage prebuilds per-group images in ws: eh-frag + exact e2
// (26624 B/group) and el-frag (24576 B/group, iff ws >= 400 KiB).
// Main: eh+e2 in LDS (26.6 KiB -> 32 waves/CU), el streamed from ws via
// global loads (L1/L2-hot; one group per XCD). 3-product screen
// (eh*xh + eh*xl + el*xh, err ~2e-3), 7-bit in-lane id (quant 2^-8),
// rare exact-f64 recheck (gate 0.03125).
#define B_   8
#define C_   192
#define HW_  4096
#define G_   8
#define K_   512
#define D_   24
#define CBSZ (K_ * D_)
#define THREADS 512              // 8 waves/block

#define FRAG_HW    12288         // 32 t * 384 hw
#define E2_OFF_HW  12288
#define EL_OFF_HW  13312         // (fallback path only; LDS [eh][e2][el])
// ws layout: 8 * [eh+e2 13312 hw] then 8 * [el 12288 hw]
#define WS_IMG_HW  13312
#define WS_EL_BASE (8 * WS_IMG_HW)
#define WS_BIG_BYTES ((8 * WS_IMG_HW + 8 * FRAG_HW) * 2)   // 409600

typedef float  f32x4 __attribute__((ext_vector_type(4)));
typedef int    i32x4 __attribute__((ext_vector_type(4)));
typedef short  s16x8 __attribute__((ext_vector_type(8)));
typedef short  s16x4 __attribute__((ext_vector_type(4)));
typedef unsigned long long u64;

static __device__ __forceinline__ unsigned umin_(unsigned a, unsigned b){return a<b?a:b;}
static __device__ __forceinline__ unsigned umax_(unsigned a, unsigned b){return a>b?a:b;}
static __device__ __forceinline__ unsigned short f2bf(float x){       // RNE f32->bf16
    unsigned u=__float_as_uint(x);
    return (unsigned short)((u + 0x7FFFu + ((u>>16)&1u))>>16);
}
static __device__ __forceinline__ float bf2f(unsigned short h){return __uint_as_float(((unsigned)h)<<16);}
// packed id9 = t<<4 | r<<2 | q  ->  code number = t*16 + q*4 + r
static __device__ __forceinline__ int dec_id(unsigned idb){
    return (int)((idb & 0x1F0u) | ((idb & 3u) << 2) | ((idb >> 2) & 3u));
}

// ---------- stage: build per-group images in ws ----------
__global__ __launch_bounds__(256) void vq_stage(
    const float* __restrict__ cb, unsigned short* __restrict__ ws, int wr_el)
{
    const int g = blockIdx.x >> 3;
    const int s = blockIdx.x & 7;              // 64-code slice of this group
    const int tid = threadIdx.x;
    const float* cbg = cb + g * CBSZ;
    unsigned short* img = ws + g * WS_IMG_HW;
    unsigned short* eli = ws + WS_EL_BASE + g * FRAG_HW;

    for (int i = tid; i < 384; i += 256) {
        int gi = s * 384 + i;
        f32x4 v = ((const f32x4*)cbg)[gi];
        int i4 = gi << 2;
        int n  = i4 / 24;                      // float4 never crosses a row
        int k0 = i4 - n * 24;
        int off = (n >> 4) * 384 + (((k0 >> 3) << 4) + (n & 15)) * 8 + (k0 & 7);
        s16x4 h, l;
        #pragma unroll
        for (int j = 0; j < 4; ++j) {
            unsigned short eh = f2bf(v[j]);
            h[j] = (short)eh;
            l[j] = (short)f2bf(v[j] - bf2f(eh));
        }
        *(s16x4*)(&img[off]) = h;              // 8B-aligned (k0&7 in {0,4})
        if (wr_el) *(s16x4*)(&eli[off]) = l;
    }
    if (tid < 64) {
        int n = s * 64 + tid;
        const float* row = cbg + n * D_;
        double s0 = 0.0, s1 = 0.0;
        #pragma unroll
        for (int j = 0; j < D_; j += 2) {
            double v0 = (double)row[j], v1 = (double)row[j+1];
            s0 = fma(v0,v0,s0); s1 = fma(v1,v1,s1);
        }
        ((float*)(img + E2_OFF_HW))[n] = (float)(256.0 + s0 + s1);
    }
}

// ------------------------------- main kernel ---------------------------------
// ELG=true : el streamed from ws (global); LDS 26624 B; grid 1024; 1 pair/wave.
// ELG=false: el built into LDS from cb;    LDS 51200 B; grid 512;  2 pairs/wave.
template<bool ELG>
__global__ __launch_bounds__(THREADS, ELG ? 8 : 4) void vq_main(
    const float* __restrict__ y, const float* __restrict__ cb,
    const unsigned short* __restrict__ ws, float* __restrict__ out)
{
    constexpr int NW    = ELG ? 1024 : 512;    // wave slots per group
    constexpr int NPAIR = ELG ? 1 : 2;
    __shared__ __align__(16) unsigned short sB[ELG ? 13312 : 25600];

    const int bid = blockIdx.x;
    const int g = bid & 7;                     // group pinned to one XCD
    const int blkg = bid >> 3;
    const int tid = threadIdx.x;
    const int wave = tid >> 6, lane = tid & 63;
    const int c = lane & 15, q = lane >> 4;

    const float* cbg = cb + g * CBSZ;

    // ---- staging: coalesced copy of eh+e2 (26624 B) ----
    {
        const char* src = (const char*)(ws + g * WS_IMG_HW);
        char* dst = (char*)sB;
        #pragma unroll
        for (int it = 0; it < 4; ++it) {
            int off = it * 8192 + tid * 16;
            if (off < 26624)
                *(i32x4*)(dst + off) = *(const i32x4*)(src + off);
        }
    }
    if constexpr (!ELG) {                      // build el from cb (coalesced)
        #pragma unroll
        for (int it = 0; it < 6; ++it) {
            int gi = it * THREADS + tid;       // 3072 float4s cover the group
            f32x4 v = ((const f32x4*)cbg)[gi];
            int i4 = gi << 2;
            int n  = i4 / 24;
            int k0 = i4 - n * 24;
            int off = (n >> 4) * 384 + (((k0 >> 3) << 4) + (n & 15)) * 8 + (k0 & 7);
            s16x4 l;
            #pragma unroll
            for (int j = 0; j < 4; ++j) {
                unsigned short eh = f2bf(v[j]);
                l[j] = (short)f2bf(v[j] - bf2f(eh));
            }
            *(s16x4*)(&sB[EL_OFF_HW + off]) = l;
        }
    }
    __syncthreads();

    float* out0 = out;
    float* out1 = out + B_*C_*HW_;
    float* out2 = out + 2*B_*C_*HW_;

    // A-fragment pointers: lanes 48..63 alias lanes 0..15 (their k=24..31
    // products multiply a zero B operand).
    const int alias8 = (lane < 48 ? lane : lane - 48) * 8;
    const unsigned short* aH = sB + alias8;
    const unsigned short* aLg = ELG ? (ws + WS_EL_BASE + g * FRAG_HW + alias8)
                                    : (const unsigned short*)nullptr;
    const unsigned short* aLs = ELG ? (const unsigned short*)nullptr
                                    : (sB + EL_OFF_HW + alias8);
    // e2 accumulator-init: lane (c,q) reg r -> code t*16 + q*4 + r
    const f32x4* e2p = (const f32x4*)((const float*)(sB + E2_OFF_HW) + (q << 2));

    const int wsid = (blkg << 3) + wave;       // [0,NW) per group

    #pragma unroll 1
    for (int p = 0; p < NPAIR; ++p) {          // pairs: (tt0, tt0+NW)
        const int tt0   = wsid + p * 2 * NW;
        const int hw    = (tt0 & 255) << 4;
        const int bimg0 = tt0 >> 8;
        int ybase[2];
        ybase[0] = (bimg0*C_ + g*D_)*HW_ + hw;
        ybase[1] = ybase[0] + (NW >> 8)*C_*HW_;

        // ---- B operands: lane (c,q<3) holds (-2x)[pos c][k=q*8+j]; q==3 -> 0 ----
        s16x8 Xh[2], Xl[2];
        #pragma unroll
        for (int ti = 0; ti < 2; ++ti) {
            unsigned hx[4], lx[4];
            if (q < 3) {
                const float* yq = y + ybase[ti] + (q*8)*HW_ + c;
                float xf[8];
                #pragma unroll
                for (int jj = 0; jj < 8; ++jj) xf[jj] = -2.0f * yq[jj*HW_];
                #pragma unroll
                for (int p2 = 0; p2 < 4; ++p2) {
                    float f0 = xf[2*p2], f1 = xf[2*p2+1];
                    unsigned u0 = __float_as_uint(f0), u1v = __float_as_uint(f1);
                    hx[p2] = (u1v & 0xFFFF0000u) | (u0 >> 16);    // trunc-hi pair
                    float l0 = f0 - __uint_as_float(u0 & 0xFFFF0000u);
                    float l1 = f1 - __uint_as_float(u1v & 0xFFFF0000u);
                    lx[p2] = (unsigned)f2bf(l0) | ((unsigned)f2bf(l1) << 16);
                }
            } else {
                hx[0]=0u; hx[1]=0u; hx[2]=0u; hx[3]=0u;
                lx[0]=0u; lx[1]=0u; lx[2]=0u; lx[3]=0u;
            }
            Xh[ti] = __builtin_bit_cast(s16x8, (i32x4){(int)hx[0],(int)hx[1],(int)hx[2],(int)hx[3]});
            Xl[ti] = __builtin_bit_cast(s16x8, (i32x4){(int)lx[0],(int)lx[1],(int)lx[2],(int)lx[3]});
        }

        // ---- fused 3-product screen; in-lane 7-bit id (quant 2^-8) ----
        unsigned b1a[2] = {~0u, ~0u}, b2a[2] = {~0u, ~0u}, b3a[2] = {~0u, ~0u};
        #pragma unroll 4
        for (int t = 0; t < 32; ++t) {
            s16x8 eh = *(const s16x8*)(aH + t * 384);
            s16x8 el;
            if constexpr (ELG) el = *(const s16x8*)(aLg + t * 384);  // L1/L2-hot
            else               el = *(const s16x8*)(aLs + t * 384);
            f32x4 e2v = e2p[t * 4];            // broadcast ds_read_b128
            f32x4 a0 = __builtin_amdgcn_mfma_f32_16x16x32_bf16(eh, Xh[0], e2v, 0,0,0);
            a0       = __builtin_amdgcn_mfma_f32_16x16x32_bf16(eh, Xl[0], a0,  0,0,0);
            a0       = __builtin_amdgcn_mfma_f32_16x16x32_bf16(el, Xh[0], a0,  0,0,0);
            f32x4 a1 = __builtin_amdgcn_mfma_f32_16x16x32_bf16(eh, Xh[1], e2v, 0,0,0);
            a1       = __builtin_amdgcn_mfma_f32_16x16x32_bf16(eh, Xl[1], a1,  0,0,0);
            a1       = __builtin_amdgcn_mfma_f32_16x16x32_bf16(el, Xh[1], a1,  0,0,0);
            #pragma unroll
            for (int r = 0; r < 4; ++r) {
                const unsigned id7 = (unsigned)((t << 2) | r);    // compile-time
                {
                    unsigned key = (__float_as_uint(a0[r]) & 0xFFFFFF80u) + id7;
                    unsigned t3, t2;
                    asm("v_med3_u32 %0, %1, %2, %3" : "=v"(t3) : "v"(key), "v"(b2a[0]), "v"(b3a[0]));
                    asm("v_med3_u32 %0, %1, %2, %3" : "=v"(t2) : "v"(key), "v"(b1a[0]), "v"(b2a[0]));
                    b3a[0] = t3; b2a[0] = t2; b1a[0] = umin_(b1a[0], key);
                }
                {
                    unsigned key = (__float_as_uint(a1[r]) & 0xFFFFFF80u) + id7;
                    unsigned t3, t2;
                    asm("v_med3_u32 %0, %1, %2, %3" : "=v"(t3) : "v"(key), "v"(b2a[1]), "v"(b3a[1]));
                    asm("v_med3_u32 %0, %1, %2, %3" : "=v"(t2) : "v"(key), "v"(b1a[1]), "v"(b2a[1]));
                    b3a[1] = t3; b2a[1] = t2; b1a[1] = umin_(b1a[1], key);
                }
            }
        }

        // ---- per-tile tail ----
        #pragma unroll
        for (int ti = 0; ti < 2; ++ti) {
            // expand to 9-bit id: (b<<2)|q -- order-safe (constant exponent 8)
            unsigned b1 = (b1a[ti] << 2) | (unsigned)q;
            unsigned b2 = (b2a[ti] << 2) | (unsigned)q;
            unsigned b3 = (b3a[ti] << 2) | (unsigned)q;
            #pragma unroll
            for (int d = 16; d < 64; d <<= 1) {   // butterfly: global top-3
                unsigned o1=__shfl_xor(b1,d,64), o2=__shfl_xor(b2,d,64), o3=__shfl_xor(b3,d,64);
                unsigned x = umax_(b1,o1);
                unsigned yv= umin_(b2,o2);
                unsigned w = umax_(b2,o2);
                unsigned z = umin_(b3,o3);
                b1 = umin_(b1,o1);
                b2 = umin_(x,yv);
                b3 = umin_(umax_(x,yv), umin_(w,z));
            }

            // gate: mantissa units of 2^-8; fire if gap < 8 units (0.03125)
            const int gap = (int)((b2 >> 9) - (b1 >> 9));
            int kwin;
            if (__ballot(gap < 8) == 0ull) {
                kwin = dec_id(b1 & 511u);
            } else {
                // exact fp64 recheck (rare): re-derive -2x from y (cache-hot)
                float xfr[8];
                if (q < 3) {
                    const float* yq = y + ybase[ti] + (q*8)*HW_ + c;
                    #pragma unroll
                    for (int jj = 0; jj < 8; ++jj) xfr[jj] = -2.0f * yq[jj*HW_];
                } else {
                    #pragma unroll
                    for (int jj = 0; jj < 8; ++jj) xfr[jj] = 0.0f;
                }
                double xd[8];
                #pragma unroll
                for (int jj = 0; jj < 8; ++jj) xd[jj] = (double)xfr[jj];
                const unsigned cands[3] = {b1, b2, b3};
                u64 bestk = ~0ull;
                #pragma unroll
                for (int ci = 0; ci < 3; ++ci) {
                    int kc = dec_id(cands[ci] & 511u);
                    double s = 0.0;
                    if (q < 3) {
                        const f32x4* ce4 = (const f32x4*)(cbg + kc*D_ + (q<<3));
                        float ef[8];
                        *(f32x4*)&ef[0] = ce4[0];
                        *(f32x4*)&ef[4] = ce4[1];
                        #pragma unroll
                        for (int jj = 0; jj < 8; ++jj) {
                            double ev = (double)ef[jj];
                            s = fma(ev, ev, s);
                            s = fma(xd[jj], ev, s);
                        }
                    }
                    s += __shfl_xor(s, 16, 64);
                    s += __shfl_xor(s, 32, 64);
                    s += 256.0;
                    u64 kk = (((u64)__double_as_longlong(s)) & ~0x1FFull) | (u64)kc;
                    bestk = kk < bestk ? kk : bestk;
                }
                kwin = (int)(bestk & 511ull);
            }

            // epilogue: lane (c,q<3) writes dims q*8..q*8+7 of pos c
            const float* cw = cbg + kwin * D_;
            if (q < 3) {
                const f32x4* cw4 = (const f32x4*)(cw + (q<<3));
                float v[8];
                *(f32x4*)&v[0] = cw4[0];
                *(f32x4*)&v[4] = cw4[1];
                const int ob = ybase[ti] + (q*8)*HW_ + c;
                #pragma unroll
                for (int jj = 0; jj < 8; ++jj) {
                    out0[ob + jj*HW_] = v[jj];
                    out1[ob + jj*HW_] = v[jj];
                }
            }
            if (lane < 16) {
                const int bimg = bimg0 + (NW >> 8)*ti;
                out2[(bimg*G_ + g)*HW_ + hw + lane] = (float)kwin;
            }
        }
    }
}

extern "C" void kernel_launch(void* const* d_in, const int* in_sizes, int n_in,
                              void* d_out, int out_size, void* d_ws, size_t ws_size,
                              hipStream_t stream) {
    const float* y  = (const float*)d_in[0];
    const float* cb = (const float*)d_in[1];
    float* out = (float*)d_out;
    unsigned short* ws = (unsigned short*)d_ws;

    const bool big = ws_size >= (size_t)WS_BIG_BYTES;   // room for el frags too?
    vq_stage<<<dim3(64), dim3(256), 0, stream>>>(cb, ws, big ? 1 : 0);
    if (big) vq_main<true ><<<dim3(1024), dim3(THREADS), 0, stream>>>(y, cb, ws, out);
    else     vq_main<false><<<dim3(512),  dim3(THREADS), 0, stream>>>(y, cb, ws, out);
}

// Round 7
// 113.069 us; speedup vs baseline: 1.0197x; 1.0015x over previous
//
#include <hip/hip_runtime.h>

// y: [B=8, C=192, H=64, W=64] f32; codebooks: [G=8, K=512, d=24] f32
// out (f32, concat): universal_ctx | y_ba | code_index [B,1,G,H,W]
// Stage prebuilds per-group images in ws: f16 eh-frag + exact e2 (+128 bias)
// and f16 el-frag (iff ws >= 400 KiB). Main: whole image in LDS (51.2 KiB),
// 1024-thread blocks, 2 blocks/CU -> 32 waves/CU, exactly 1 pair/wave.
// Screen: 3-product f16 MFMA (eh*xh + eh*xl + el*xh, eps ~5e-5), 7-bit
// in-lane id, gate = 2 quantum units + small-value guard, rare f64 recheck.
#define B_   8
#define C_   192
#define HW_  4096
#define G_   8
#define K_   512
#define D_   24
#define CBSZ (K_ * D_)
#define THREADS 1024             // 16 waves/block
#define NBLOCKS 512              // 2 blocks/CU; 64 blocks/group; 1 pair/wave

// halfword-unit layout per group (ws big-path and LDS are identical):
// [eh frag 12288][e2 512*f32 = 1024][el frag 12288] = 25600 hw = 51200 B
#define FRAG_HW    12288         // 32 t * 384 hw
#define E2_OFF_HW  12288
#define EL_OFF_HW  13312
#define IMG_HW     25600
#define WS_SMALL_HW 13312        // fallback ws: [eh|e2] only (212992 B total)
#define WS_BIG_BYTES (G_ * IMG_HW * 2)   // 409600

typedef float  f32x4 __attribute__((ext_vector_type(4)));
typedef int    i32x4 __attribute__((ext_vector_type(4)));
typedef short  s16x8 __attribute__((ext_vector_type(8)));
typedef short  s16x4 __attribute__((ext_vector_type(4)));
typedef _Float16 h16x8 __attribute__((ext_vector_type(8)));
typedef unsigned long long u64;

static __device__ __forceinline__ unsigned umin_(unsigned a, unsigned b){return a<b?a:b;}
static __device__ __forceinline__ unsigned umax_(unsigned a, unsigned b){return a>b?a:b;}
// packed id9 = t<<4 | r<<2 | q  ->  code number = t*16 + q*4 + r
static __device__ __forceinline__ int dec_id(unsigned idb){
    return (int)((idb & 0x1F0u) | ((idb & 3u) << 2) | ((idb >> 2) & 3u));
}
// pack two f32 -> two f16 (RTZ), as a 32-bit word
static __device__ __forceinline__ unsigned pkrtz(float a, float b){
    return __builtin_bit_cast(unsigned, __builtin_amdgcn_cvt_pkrtz(a, b));
}
static __device__ __forceinline__ float lo16f(unsigned w){
    return (float)__builtin_bit_cast(_Float16, (unsigned short)(w & 0xFFFFu));
}
static __device__ __forceinline__ float hi16f(unsigned w){
    return (float)__builtin_bit_cast(_Float16, (unsigned short)(w >> 16));
}

// ---------- stage: build per-group f16 images in ws ----------
__global__ __launch_bounds__(256) void vq_stage(
    const float* __restrict__ cb, unsigned short* __restrict__ ws, int big)
{
    const int g = blockIdx.x >> 3;
    const int s = blockIdx.x & 7;              // 64-code slice of this group
    const int tid = threadIdx.x;
    const float* cbg = cb + g * CBSZ;
    unsigned short* img = ws + g * (big ? IMG_HW : WS_SMALL_HW);

    for (int i = tid; i < 384; i += 256) {
        int gi = s * 384 + i;
        f32x4 v = ((const f32x4*)cbg)[gi];
        int i4 = gi << 2;
        int n  = i4 / 24;                      // float4 never crosses a row
        int k0 = i4 - n * 24;
        int off = (n >> 4) * 384 + (((k0 >> 3) << 4) + (n & 15)) * 8 + (k0 & 7);
        s16x4 h, l;
        #pragma unroll
        for (int j = 0; j < 4; ++j) {
            _Float16 eh = (_Float16)v[j];                  // RNE; residual exact
            _Float16 el = (_Float16)(v[j] - (float)eh);
            h[j] = __builtin_bit_cast(short, eh);
            l[j] = __builtin_bit_cast(short, el);
        }
        *(s16x4*)(&img[off]) = h;              // 8B-aligned (k0&7 in {0,4})
        if (big) *(s16x4*)(&img[EL_OFF_HW + off]) = l;
    }
    if (tid < 64) {                            // exact e2, +128 bias
        int n = s * 64 + tid;
        const float* row = cbg + n * D_;
        double s0 = 0.0, s1 = 0.0;
        #pragma unroll
        for (int j = 0; j < D_; j += 2) {
            double v0 = (double)row[j], v1 = (double)row[j+1];
            s0 = fma(v0,v0,s0); s1 = fma(v1,v1,s1);
        }
        ((float*)(img + E2_OFF_HW))[n] = (float)(128.0 + s0 + s1);
    }
}

// ------------------------------- main kernel ---------------------------------
template<bool BIG>
__global__ __launch_bounds__(THREADS, 8) void vq_main(
    const float* __restrict__ y, const float* __restrict__ cb,
    const unsigned short* __restrict__ ws, float* __restrict__ out)
{
    __shared__ __align__(16) unsigned short sB[IMG_HW];   // 51200 B

    const int bid = blockIdx.x;
    const int g = bid & 7;                     // group pinned to one XCD
    const int blkg = bid >> 3;                 // 64 blocks per group
    const int tid = threadIdx.x;
    const int wave = tid >> 6, lane = tid & 63;
    const int c = lane & 15, q = lane >> 4;

    const float* cbg = cb + g * CBSZ;

    // ---- staging ----
    if constexpr (BIG) {                       // one contiguous 51200 B copy
        const char* src = (const char*)(ws + g * IMG_HW);
        char* dst = (char*)sB;
        #pragma unroll
        for (int it = 0; it < 4; ++it) {
            int off = it * 16384 + tid * 16;
            if (off < 51200)
                *(i32x4*)(dst + off) = *(const i32x4*)(src + off);
        }
    } else {                                   // copy eh+e2; build el from cb
        const char* src = (const char*)(ws + g * WS_SMALL_HW);
        char* dst = (char*)sB;
        #pragma unroll
        for (int it = 0; it < 2; ++it) {
            int off = it * 16384 + tid * 16;
            if (off < 26624)
                *(i32x4*)(dst + off) = *(const i32x4*)(src + off);
        }
        #pragma unroll
        for (int it = 0; it < 3; ++it) {
            int gi = it * THREADS + tid;       // 3072 float4s cover the group
            f32x4 v = ((const f32x4*)cbg)[gi];
            int i4 = gi << 2;
            int n  = i4 / 24;
            int k0 = i4 - n * 24;
            int off = (n >> 4) * 384 + (((k0 >> 3) << 4) + (n & 15)) * 8 + (k0 & 7);
            s16x4 l;
            #pragma unroll
            for (int j = 0; j < 4; ++j) {
                _Float16 eh = (_Float16)v[j];  // must match stage's RNE eh
                l[j] = __builtin_bit_cast(short, (_Float16)(v[j] - (float)eh));
            }
            *(s16x4*)(&sB[EL_OFF_HW + off]) = l;
        }
    }
    __syncthreads();

    float* out0 = out;
    float* out1 = out + B_*C_*HW_;
    float* out2 = out + 2*B_*C_*HW_;

    // A-fragment pointer: lanes 48..63 alias lanes 0..15 (their k=24..31
    // products multiply a zero B operand). el at +EL_OFF_HW via imm offset.
    const unsigned short* aH = sB + (lane < 48 ? lane : lane - 48) * 8;
    // e2 accumulator-init: lane (c,q) reg r -> code t*16 + q*4 + r
    const f32x4* e2p = (const f32x4*)((const float*)(sB + E2_OFF_HW) + (q << 2));

    const int wsid = (blkg << 4) + wave;       // [0,1024) per group
    const int hw    = (wsid & 255) << 4;
    const int bimg0 = wsid >> 8;               // 0..3; pair = (bimg0, bimg0+4)
    int ybase[2];
    ybase[0] = (bimg0*C_ + g*D_)*HW_ + hw;
    ybase[1] = ybase[0] + 4*C_*HW_;

    // ---- B operands: lane (c,q<3) holds (-2x)[pos c][k=q*8+j]; q==3 -> 0 ----
    h16x8 Xh[2], Xl[2];
    #pragma unroll
    for (int ti = 0; ti < 2; ++ti) {
        unsigned hx[4], lx[4];
        if (q < 3) {
            const float* yq = y + ybase[ti] + (q*8)*HW_ + c;
            float xf[8];
            #pragma unroll
            for (int jj = 0; jj < 8; ++jj) xf[jj] = -2.0f * yq[jj*HW_];
            #pragma unroll
            for (int p2 = 0; p2 < 4; ++p2) {
                float f0 = xf[2*p2], f1 = xf[2*p2+1];
                unsigned hw32 = pkrtz(f0, f1);            // RTZ: residual exact
                float r0 = f0 - lo16f(hw32), r1 = f1 - hi16f(hw32);
                hx[p2] = hw32;
                lx[p2] = pkrtz(r0, r1);
            }
        } else {
            hx[0]=0u; hx[1]=0u; hx[2]=0u; hx[3]=0u;
            lx[0]=0u; lx[1]=0u; lx[2]=0u; lx[3]=0u;
        }
        Xh[ti] = __builtin_bit_cast(h16x8, (i32x4){(int)hx[0],(int)hx[1],(int)hx[2],(int)hx[3]});
        Xl[ti] = __builtin_bit_cast(h16x8, (i32x4){(int)lx[0],(int)lx[1],(int)lx[2],(int)lx[3]});
    }

    // ---- fused 3-product f16 screen; in-lane 7-bit id ----
    unsigned b1a[2] = {~0u, ~0u}, b2a[2] = {~0u, ~0u}, b3a[2] = {~0u, ~0u};
    #pragma unroll 4
    for (int t = 0; t < 32; ++t) {
        h16x8 eh = __builtin_bit_cast(h16x8, *(const s16x8*)(aH + t * 384));
        h16x8 el = __builtin_bit_cast(h16x8, *(const s16x8*)(aH + EL_OFF_HW + t * 384));
        f32x4 e2v = e2p[t * 4];                // broadcast ds_read_b128
        f32x4 a0 = __builtin_amdgcn_mfma_f32_16x16x32_f16(eh, Xh[0], e2v, 0,0,0);
        a0       = __builtin_amdgcn_mfma_f32_16x16x32_f16(eh, Xl[0], a0,  0,0,0);
        a0       = __builtin_amdgcn_mfma_f32_16x16x32_f16(el, Xh[0], a0,  0,0,0);
        f32x4 a1 = __builtin_amdgcn_mfma_f32_16x16x32_f16(eh, Xh[1], e2v, 0,0,0);
        a1       = __builtin_amdgcn_mfma_f32_16x16x32_f16(eh, Xl[1], a1,  0,0,0);
        a1       = __builtin_amdgcn_mfma_f32_16x16x32_f16(el, Xh[1], a1,  0,0,0);
        #pragma unroll
        for (int r = 0; r < 4; ++r) {
            const unsigned id7 = (unsigned)((t << 2) | r);    // compile-time
            {
                unsigned key = (__float_as_uint(a0[r]) & 0xFFFFFF80u) + id7;
                unsigned t3, t2;
                asm("v_med3_u32 %0, %1, %2, %3" : "=v"(t3) : "v"(key), "v"(b2a[0]), "v"(b3a[0]));
                asm("v_med3_u32 %0, %1, %2, %3" : "=v"(t2) : "v"(key), "v"(b1a[0]), "v"(b2a[0]));
                b3a[0] = t3; b2a[0] = t2; b1a[0] = umin_(b1a[0], key);
            }
            {
                unsigned key = (__float_as_uint(a1[r]) & 0xFFFFFF80u) + id7;
                unsigned t3, t2;
                asm("v_med3_u32 %0, %1, %2, %3" : "=v"(t3) : "v"(key), "v"(b2a[1]), "v"(b3a[1]));
                asm("v_med3_u32 %0, %1, %2, %3" : "=v"(t2) : "v"(key), "v"(b1a[1]), "v"(b2a[1]));
                b3a[1] = t3; b2a[1] = t2; b1a[1] = umin_(b1a[1], key);
            }
        }
    }

    // ---- per-tile tail ----
    #pragma unroll
    for (int ti = 0; ti < 2; ++ti) {
        // expand to 9-bit id: (b<<2)|q -- monotone (values >= 2.0 keep a
        // constant leading exponent bit; screen values live in ~[40, 512))
        unsigned b1 = (b1a[ti] << 2) | (unsigned)q;
        unsigned b2 = (b2a[ti] << 2) | (unsigned)q;
        unsigned b3 = (b3a[ti] << 2) | (unsigned)q;
        #pragma unroll
        for (int d = 16; d < 64; d <<= 1) {    // butterfly: global top-3
            unsigned o1=__shfl_xor(b1,d,64), o2=__shfl_xor(b2,d,64), o3=__shfl_xor(b3,d,64);
            unsigned x = umax_(b1,o1);
            unsigned yv= umin_(b2,o2);
            unsigned w = umax_(b2,o2);
            unsigned z = umin_(b3,o3);
            b1 = umin_(b1,o1);
            b2 = umin_(x,yv);
            b3 = umin_(umax_(x,yv), umin_(w,z));
        }

        // gate: fire if int-gap < 2 quanta, or winner below 64.0 (step too
        // fine there to certify against screen error) -- 0x0A000000 = bits(64.f)<<2
        const int gap = (int)((b2 >> 9) - (b1 >> 9));
        int kwin;
        if (__ballot((gap < 2) || (b1 < 0x0A000000u)) == 0ull) {
            kwin = dec_id(b1 & 511u);
        } else {
            // exact fp64 recheck (rare): re-derive -2x from y (cache-hot)
            float xfr[8];
            if (q < 3) {
                const float* yq = y + ybase[ti] + (q*8)*HW_ + c;
                #pragma unroll
                for (int jj = 0; jj < 8; ++jj) xfr[jj] = -2.0f * yq[jj*HW_];
            } else {
                #pragma unroll
                for (int jj = 0; jj < 8; ++jj) xfr[jj] = 0.0f;
            }
            double xd[8];
            #pragma unroll
            for (int jj = 0; jj < 8; ++jj) xd[jj] = (double)xfr[jj];
            const unsigned cands[3] = {b1, b2, b3};
            u64 bestk = ~0ull;
            #pragma unroll
            for (int ci = 0; ci < 3; ++ci) {
                int kc = dec_id(cands[ci] & 511u);
                double s = 0.0;
                if (q < 3) {
                    const f32x4* ce4 = (const f32x4*)(cbg + kc*D_ + (q<<3));
                    float ef[8];
                    *(f32x4*)&ef[0] = ce4[0];
                    *(f32x4*)&ef[4] = ce4[1];
                    #pragma unroll
                    for (int jj = 0; jj < 8; ++jj) {
                        double ev = (double)ef[jj];
                        s = fma(ev, ev, s);
                        s = fma(xd[jj], ev, s);
                    }
                }
                s += __shfl_xor(s, 16, 64);
                s += __shfl_xor(s, 32, 64);
                s += 128.0;
                u64 kk = (((u64)__double_as_longlong(s)) & ~0x1FFull) | (u64)kc;
                bestk = kk < bestk ? kk : bestk;
            }
            kwin = (int)(bestk & 511ull);
        }

        // epilogue: lane (c,q<3) writes dims q*8..q*8+7 of pos c
        const float* cw = cbg + kwin * D_;
        if (q < 3) {
            const f32x4* cw4 = (const f32x4*)(cw + (q<<3));
            float v[8];
            *(f32x4*)&v[0] = cw4[0];
            *(f32x4*)&v[4] = cw4[1];
            const int ob = ybase[ti] + (q*8)*HW_ + c;
            #pragma unroll
            for (int jj = 0; jj < 8; ++jj) {
                out0[ob + jj*HW_] = v[jj];
                out1[ob + jj*HW_] = v[jj];
            }
        }
        if (lane < 16) {
            const int bimg = bimg0 + 4*ti;
            out2[(bimg*G_ + g)*HW_ + hw + lane] = (float)kwin;
        }
    }
}

extern "C" void kernel_launch(void* const* d_in, const int* in_sizes, int n_in,
                              void* d_out, int out_size, void* d_ws, size_t ws_size,
                              hipStream_t stream) {
    const float* y  = (const float*)d_in[0];
    const float* cb = (const float*)d_in[1];
    float* out = (float*)d_out;
    unsigned short* ws = (unsigned short*)d_ws;

    const bool big = ws_size >= (size_t)WS_BIG_BYTES;   // room for el frags too?
    vq_stage<<<dim3(64), dim3(256), 0, stream>>>(cb, ws, big ? 1 : 0);
    if (big) vq_main<true ><<<dim3(NBLOCKS), dim3(THREADS), 0, stream>>>(y, cb, ws, out);
    else     vq_main<false><<<dim3(NBLOCKS), dim3(THREADS), 0, stream>>>(y, cb, ws, out);
}

// Round 8
// 109.549 us; speedup vs baseline: 1.0525x; 1.0321x over previous
//
#include <hip/hip_runtime.h>

// y: [B=8, C=192, H=64, W=64] f32; codebooks: [G=8, K=512, d=24] f32
// out (f32, concat): universal_ctx | y_ba | code_index [B,1,G,H,W]
// Stage prebuilds per-group f16 eh-images in ws (32 KiB/group, 256 KiB total):
// k<24 = f16-hi code fragments; k=24,25 cols (lanes 48..63) = exact-f64-derived
// f16 hi/lo of ||e||^2. Main kernel: eh copied to LDS, el (f16 residuals) built
// from cb with zeroed k>=24 lanes; screen = 3 f16 MFMAs per t with X[q=3] =
// (1,1,0,..) so e2 rides the matrix op (no e2 ds_read). acc init = 128 const.
// Fully-unrolled t-loop (imm LDS offsets, literal ids). Gate 2 quanta + <64
// guard -> rare exact-f64 recheck.
#define B_   8
#define C_   192
#define HW_  4096
#define G_   8
#define K_   512
#define D_   24
#define CBSZ (K_ * D_)
#define THREADS 1024             // 16 waves/block
#define NBLOCKS 512              // 2 blocks/CU; 64 blocks/group; 1 pair/wave

// halfword units: eh frag 32 t * 512 = 16384; el frag same (k>=24 lanes zero)
#define EH_HW    16384
#define EL_OFF   16384
#define LDS_HW   32768           // 65536 B -> 2 blocks/CU (128 KiB of 160)
#define WS_G_HW  16384           // ws: 8 * 32768 B = 262144 B (256 KiB exactly)

typedef float  f32x4 __attribute__((ext_vector_type(4)));
typedef int    i32x4 __attribute__((ext_vector_type(4)));
typedef short  s16x8 __attribute__((ext_vector_type(8)));
typedef short  s16x4 __attribute__((ext_vector_type(4)));
typedef _Float16 h16x8 __attribute__((ext_vector_type(8)));
typedef unsigned long long u64;

static __device__ __forceinline__ unsigned umin_(unsigned a, unsigned b){return a<b?a:b;}
static __device__ __forceinline__ unsigned umax_(unsigned a, unsigned b){return a>b?a:b;}
// packed id9 = t<<4 | r<<2 | q  ->  code number = t*16 + q*4 + r
static __device__ __forceinline__ int dec_id(unsigned idb){
    return (int)((idb & 0x1F0u) | ((idb & 3u) << 2) | ((idb >> 2) & 3u));
}
static __device__ __forceinline__ unsigned pkrtz(float a, float b){
    return __builtin_bit_cast(unsigned, __builtin_amdgcn_cvt_pkrtz(a, b));
}
static __device__ __forceinline__ float lo16f(unsigned w){
    return (float)__builtin_bit_cast(_Float16, (unsigned short)(w & 0xFFFFu));
}
static __device__ __forceinline__ float hi16f(unsigned w){
    return (float)__builtin_bit_cast(_Float16, (unsigned short)(w >> 16));
}

// ---------- stage: build per-group eh images (with e2 hi/lo cols) in ws ----------
__global__ __launch_bounds__(256) void vq_stage(
    const float* __restrict__ cb, unsigned short* __restrict__ ws)
{
    const int g = blockIdx.x >> 3;
    const int s = blockIdx.x & 7;              // 64-code slice of this group
    const int tid = threadIdx.x;
    const float* cbg = cb + g * CBSZ;
    unsigned short* img = ws + g * WS_G_HW;

    for (int i = tid; i < 384; i += 256) {
        int gi = s * 384 + i;
        f32x4 v = ((const f32x4*)cbg)[gi];
        int i4 = gi << 2;
        int n  = i4 / 24;                      // float4 never crosses a row
        int k0 = i4 - n * 24;
        int off = (n >> 4) * 512 + (((k0 >> 3) << 4) + (n & 15)) * 8 + (k0 & 7);
        s16x4 h;
        #pragma unroll
        for (int j = 0; j < 4; ++j)
            h[j] = __builtin_bit_cast(short, (_Float16)v[j]);
        *(s16x4*)(&img[off]) = h;              // 8B-aligned (k0&7 in {0,4})
    }
    if (tid < 64) {                            // e2 hi/lo cols at k=24,25
        int n = s * 64 + tid;
        const float* row = cbg + n * D_;
        double s0 = 0.0, s1 = 0.0;
        #pragma unroll
        for (int j = 0; j < D_; j += 2) {
            double v0 = (double)row[j], v1 = (double)row[j+1];
            s0 = fma(v0,v0,s0); s1 = fma(v1,v1,s1);
        }
        double e2 = s0 + s1;                   // exact-ish ||e||^2
        _Float16 hi = (_Float16)(float)e2;
        _Float16 lo = (_Float16)(float)(e2 - (double)(float)hi);
        s16x8 pack = { __builtin_bit_cast(short, hi),
                       __builtin_bit_cast(short, lo), 0,0,0,0,0,0 };
        *(s16x8*)(&img[(n >> 4) * 512 + (48 + (n & 15)) * 8]) = pack;
    }
}

// ------------------------------- main kernel ---------------------------------
__global__ __launch_bounds__(THREADS, 8) void vq_main(
    const float* __restrict__ y, const float* __restrict__ cb,
    const unsigned short* __restrict__ ws, float* __restrict__ out)
{
    __shared__ __align__(16) unsigned short sB[LDS_HW];   // 65536 B

    const int bid = blockIdx.x;
    const int g = bid & 7;                     // group pinned to one XCD
    const int blkg = bid >> 3;                 // 64 blocks per group
    const int tid = threadIdx.x;
    const int wave = tid >> 6, lane = tid & 63;
    const int c = lane & 15, q = lane >> 4;

    const float* cbg = cb + g * CBSZ;

    // ---- staging: eh coalesced copy (32768 B, exactly 2 sweeps) ----
    {
        const char* src = (const char*)(ws + g * WS_G_HW);
        char* dst = (char*)sB;
        *(i32x4*)(dst + tid*16)         = *(const i32x4*)(src + tid*16);
        *(i32x4*)(dst + 16384 + tid*16) = *(const i32x4*)(src + 16384 + tid*16);
    }
    // ---- el: f16 residuals built from cb (coalesced, L2-hot) ----
    #pragma unroll
    for (int it = 0; it < 3; ++it) {
        int gi = it * THREADS + tid;           // 3072 float4s cover the group
        f32x4 v = ((const f32x4*)cbg)[gi];
        int i4 = gi << 2;
        int n  = i4 / 24;
        int k0 = i4 - n * 24;
        int off = (n >> 4) * 512 + (((k0 >> 3) << 4) + (n & 15)) * 8 + (k0 & 7);
        s16x4 l;
        #pragma unroll
        for (int j = 0; j < 4; ++j) {
            _Float16 eh = (_Float16)v[j];      // must match stage's RNE eh
            l[j] = __builtin_bit_cast(short, (_Float16)(v[j] - (float)eh));
        }
        *(s16x4*)(&sB[EL_OFF + off]) = l;
    }
    // zero el's k=24..31 lanes (they multiply X[q=3]=(1,1,..) -- must be 0)
    if (tid < 512) {
        int t = tid >> 4, cc = tid & 15;
        s16x8 z = {0,0,0,0,0,0,0,0};
        *(s16x8*)(&sB[EL_OFF + t * 512 + (48 + cc) * 8]) = z;
    }
    __syncthreads();

    float* out0 = out;
    float* out1 = out + B_*C_*HW_;
    float* out2 = out + 2*B_*C_*HW_;

    const unsigned short* aH = sB + lane * 8;            // stride 512 hw / t
    const unsigned short* aL = sB + EL_OFF + lane * 8;   // stride 512 hw / t

    const int wsid = (blkg << 4) + wave;       // [0,1024) per group
    const int hw    = (wsid & 255) << 4;
    const int bimg0 = wsid >> 8;               // 0..3; pair = (bimg0, bimg0+4)
    int ybase[2];
    ybase[0] = (bimg0*C_ + g*D_)*HW_ + hw;
    ybase[1] = ybase[0] + 4*C_*HW_;

    // ---- B operands: lane (c,q<3) holds (-2x)[pos c][k=q*8+j];
    //      q==3 -> Xh=(1,1,0,..) to pick up e2 hi/lo, Xl=0 ----
    h16x8 Xh[2], Xl[2];
    #pragma unroll
    for (int ti = 0; ti < 2; ++ti) {
        unsigned hx[4], lx[4];
        if (q < 3) {
            const float* yq = y + ybase[ti] + (q*8)*HW_ + c;
            float xf[8];
            #pragma unroll
            for (int jj = 0; jj < 8; ++jj) xf[jj] = -2.0f * yq[jj*HW_];
            #pragma unroll
            for (int p2 = 0; p2 < 4; ++p2) {
                float f0 = xf[2*p2], f1 = xf[2*p2+1];
                unsigned hw32 = pkrtz(f0, f1);            // RTZ: residual exact
                float r0 = f0 - lo16f(hw32), r1 = f1 - hi16f(hw32);
                hx[p2] = hw32;
                lx[p2] = pkrtz(r0, r1);
            }
        } else {
            hx[0]=0x3C003C00u; hx[1]=0u; hx[2]=0u; hx[3]=0u;   // (1.0h, 1.0h)
            lx[0]=0u; lx[1]=0u; lx[2]=0u; lx[3]=0u;
        }
        Xh[ti] = __builtin_bit_cast(h16x8, (i32x4){(int)hx[0],(int)hx[1],(int)hx[2],(int)hx[3]});
        Xl[ti] = __builtin_bit_cast(h16x8, (i32x4){(int)lx[0],(int)lx[1],(int)lx[2],(int)lx[3]});
    }

    const f32x4 cbias = {128.0f, 128.0f, 128.0f, 128.0f};

    // ---- fused 3-product f16 screen; e2 rides the eh*Xh MFMA ----
    unsigned b1a[2] = {~0u, ~0u}, b2a[2] = {~0u, ~0u}, b3a[2] = {~0u, ~0u};
    #pragma unroll
    for (int t = 0; t < 32; ++t) {
        h16x8 eh = __builtin_bit_cast(h16x8, *(const s16x8*)(aH + t * 512));
        h16x8 el = __builtin_bit_cast(h16x8, *(const s16x8*)(aL + t * 512));
        f32x4 a0 = __builtin_amdgcn_mfma_f32_16x16x32_f16(eh, Xh[0], cbias, 0,0,0);
        a0       = __builtin_amdgcn_mfma_f32_16x16x32_f16(eh, Xl[0], a0,   0,0,0);
        a0       = __builtin_amdgcn_mfma_f32_16x16x32_f16(el, Xh[0], a0,   0,0,0);
        f32x4 a1 = __builtin_amdgcn_mfma_f32_16x16x32_f16(eh, Xh[1], cbias, 0,0,0);
        a1       = __builtin_amdgcn_mfma_f32_16x16x32_f16(eh, Xl[1], a1,   0,0,0);
        a1       = __builtin_amdgcn_mfma_f32_16x16x32_f16(el, Xh[1], a1,   0,0,0);
        #pragma unroll
        for (int r = 0; r < 4; ++r) {
            const unsigned id7 = (unsigned)((t << 2) | r);    // compile-time
            {
                unsigned key = (__float_as_uint(a0[r]) & 0xFFFFFF80u) + id7;
                unsigned t3, t2;
                asm("v_med3_u32 %0, %1, %2, %3" : "=v"(t3) : "v"(key), "v"(b2a[0]), "v"(b3a[0]));
                asm("v_med3_u32 %0, %1, %2, %3" : "=v"(t2) : "v"(key), "v"(b1a[0]), "v"(b2a[0]));
                b3a[0] = t3; b2a[0] = t2; b1a[0] = umin_(b1a[0], key);
            }
            {
                unsigned key = (__float_as_uint(a1[r]) & 0xFFFFFF80u) + id7;
                unsigned t3, t2;
                asm("v_med3_u32 %0, %1, %2, %3" : "=v"(t3) : "v"(key), "v"(b2a[1]), "v"(b3a[1]));
                asm("v_med3_u32 %0, %1, %2, %3" : "=v"(t2) : "v"(key), "v"(b1a[1]), "v"(b2a[1]));
                b3a[1] = t3; b2a[1] = t2; b1a[1] = umin_(b1a[1], key);
            }
        }
    }

    // ---- per-tile tail ----
    #pragma unroll
    for (int ti = 0; ti < 2; ++ti) {
        // expand to 9-bit id: (b<<2)|q -- monotone for our value range
        unsigned b1 = (b1a[ti] << 2) | (unsigned)q;
        unsigned b2 = (b2a[ti] << 2) | (unsigned)q;
        unsigned b3 = (b3a[ti] << 2) | (unsigned)q;
        #pragma unroll
        for (int d = 16; d < 64; d <<= 1) {    // butterfly: global top-3
            unsigned o1=__shfl_xor(b1,d,64), o2=__shfl_xor(b2,d,64), o3=__shfl_xor(b3,d,64);
            unsigned x = umax_(b1,o1);
            unsigned yv= umin_(b2,o2);
            unsigned w = umax_(b2,o2);
            unsigned z = umin_(b3,o3);
            b1 = umin_(b1,o1);
            b2 = umin_(x,yv);
            b3 = umin_(umax_(x,yv), umin_(w,z));
        }

        // gate: fire if int-gap < 2 quanta, or winner below 64.0
        const int gap = (int)((b2 >> 9) - (b1 >> 9));
        int kwin;
        if (__ballot((gap < 2) || (b1 < 0x0A000000u)) == 0ull) {
            kwin = dec_id(b1 & 511u);
        } else {
            // exact fp64 recheck (rare): re-derive -2x from y (cache-hot)
            float xfr[8];
            if (q < 3) {
                const float* yq = y + ybase[ti] + (q*8)*HW_ + c;
                #pragma unroll
                for (int jj = 0; jj < 8; ++jj) xfr[jj] = -2.0f * yq[jj*HW_];
            } else {
                #pragma unroll
                for (int jj = 0; jj < 8; ++jj) xfr[jj] = 0.0f;
            }
            double xd[8];
            #pragma unroll
            for (int jj = 0; jj < 8; ++jj) xd[jj] = (double)xfr[jj];
            const unsigned cands[3] = {b1, b2, b3};
            u64 bestk = ~0ull;
            #pragma unroll
            for (int ci = 0; ci < 3; ++ci) {
                int kc = dec_id(cands[ci] & 511u);
                double s = 0.0;
                if (q < 3) {
                    const f32x4* ce4 = (const f32x4*)(cbg + kc*D_ + (q<<3));
                    float ef[8];
                    *(f32x4*)&ef[0] = ce4[0];
                    *(f32x4*)&ef[4] = ce4[1];
                    #pragma unroll
                    for (int jj = 0; jj < 8; ++jj) {
                        double ev = (double)ef[jj];
                        s = fma(ev, ev, s);
                        s = fma(xd[jj], ev, s);
                    }
                }
                s += __shfl_xor(s, 16, 64);
                s += __shfl_xor(s, 32, 64);
                s += 128.0;
                u64 kk = (((u64)__double_as_longlong(s)) & ~0x1FFull) | (u64)kc;
                bestk = kk < bestk ? kk : bestk;
            }
            kwin = (int)(bestk & 511ull);
        }

        // epilogue: lane (c,q<3) writes dims q*8..q*8+7 of pos c
        const float* cw = cbg + kwin * D_;
        if (q < 3) {
            const f32x4* cw4 = (const f32x4*)(cw + (q<<3));
            float v[8];
            *(f32x4*)&v[0] = cw4[0];
            *(f32x4*)&v[4] = cw4[1];
            const int ob = ybase[ti] + (q*8)*HW_ + c;
            #pragma unroll
            for (int jj = 0; jj < 8; ++jj) {
                out0[ob + jj*HW_] = v[jj];
                out1[ob + jj*HW_] = v[jj];
            }
        }
        if (lane < 16) {
            const int bimg = bimg0 + 4*ti;
            out2[(bimg*G_ + g)*HW_ + hw + lane] = (float)kwin;
        }
    }
}

extern "C" void kernel_launch(void* const* d_in, const int* in_sizes, int n_in,
                              void* d_out, int out_size, void* d_ws, size_t ws_size,
                              hipStream_t stream) {
    const float* y  = (const float*)d_in[0];
    const float* cb = (const float*)d_in[1];
    float* out = (float*)d_out;
    unsigned short* ws = (unsigned short*)d_ws;   // needs exactly 256 KiB

    vq_stage<<<dim3(64), dim3(256), 0, stream>>>(cb, ws);
    vq_main<<<dim3(NBLOCKS), dim3(THREADS), 0, stream>>>(y, cb, ws, out);
}